// Round 1
// baseline (345.921 us; speedup 1.0000x reference)
//
#include <hip/hip_runtime.h>
#include <hip/hip_cooperative_groups.h>

namespace cg = cooperative_groups;

typedef __bf16 bf16x8 __attribute__((ext_vector_type(8)));
typedef float f32x4 __attribute__((ext_vector_type(4)));
typedef unsigned int u32x4 __attribute__((ext_vector_type(4)));

__device__ __forceinline__ unsigned short f2bf(float f) {
  unsigned int u = __float_as_uint(f);
  u += 0x7FFFu + ((u >> 16) & 1u);   // round-to-nearest-even
  return (unsigned short)(u >> 16);
}

__device__ __forceinline__ bf16x8 load_frag(const unsigned short* p) {
  u32x4 v = *(const u32x4*)p;
  return __builtin_bit_cast(bf16x8, v);
}

// ---------------------------------------------------------------------------
// One conversion unit = 4 consecutive floats of one (batch, obj) row.
// Zero-pads object rows O..OP-1 (required: MFMA consumes padded rows).
// ---------------------------------------------------------------------------
template<int O, int OP>
__device__ __forceinline__ void conv_unit(const float* __restrict__ src,
                                          unsigned short* __restrict__ dst,
                                          int rel)
{
  const int d4 = rel & 31;
  const int o  = (rel >> 5) % OP;          // compile-time OP -> magic-mul
  const int bb = rel / (OP * 32);
  ushort4 outv; outv.x = 0; outv.y = 0; outv.z = 0; outv.w = 0;
  if (o < O) {
    const float4 v = *(const float4*)(src + ((bb * O + o) << 7) + (d4 << 2));
    outv.x = f2bf(v.x); outv.y = f2bf(v.y); outv.z = f2bf(v.z); outv.w = f2bf(v.w);
  }
  *(ushort4*)(dst + (size_t)rel * 4) = outv;
}

// ---------------------------------------------------------------------------
// t2i pooled score, TWO images per block vs one 16-caption group. Verified
// D mapping: col=lane&15 (B-row), row=(lane>>4)*4+reg (object). Unchanged
// from the verified R-series kernel.
// ---------------------------------------------------------------------------
template<int MT, int W>
__device__ __forceinline__ void t2i_im2(
    const unsigned short* __restrict__ A,    // [128, MT*16, 128] bf16
    const unsigned short* __restrict__ Bw,   // [128, W, 128] bf16
    const int* __restrict__ obj_l, const int* __restrict__ cap_l,
    float* __restrict__ pooled,              // [128,128] fp32
    int vb, float* wmax)                     // wmax LDS >= 2*16*W
{
  const int ig  = vb >> 3;             // 0..63 -> images 2*ig, 2*ig+1
  const int i0  = ig * 2;
  const int cg0 = (vb & 7) * 16;
  const int tid = threadIdx.x;
  const int wv = tid >> 6, lane = tid & 63;
  const int quad = lane >> 4, n16 = lane & 15;
  const int ol0 = obj_l[i0], ol1 = obj_l[i0 + 1];

  bf16x8 af[2][MT][4];
#pragma unroll
  for (int im = 0; im < 2; ++im) {
    const unsigned short* Ab =
        A + (((size_t)(i0 + im) * (MT * 16) + n16) << 7) + quad * 8;
#pragma unroll
    for (int t = 0; t < MT; ++t)
#pragma unroll
      for (int s = 0; s < 4; ++s)
        af[im][t][s] = load_frag(Ab + ((t * 16) << 7) + s * 32);
  }

  const unsigned short* Bbase = Bw + (((size_t)cg0 * W + n16) << 7) + quad * 8;

  for (int nt = wv; nt < W; nt += 4) {     // NT = 16*W/16 = W tiles, exact
    const unsigned short* bp = Bbase + ((nt * 16) << 7);
    bf16x8 bfrag[4];
#pragma unroll
    for (int s = 0; s < 4; ++s) bfrag[s] = load_frag(bp + s * 32);

    f32x4 acc[2][MT];
#pragma unroll
    for (int im = 0; im < 2; ++im)
#pragma unroll
      for (int t = 0; t < MT; ++t) { f32x4 z = {0.f,0.f,0.f,0.f}; acc[im][t] = z; }
#pragma unroll
    for (int s = 0; s < 4; ++s)
#pragma unroll
      for (int im = 0; im < 2; ++im)
#pragma unroll
        for (int t = 0; t < MT; ++t)
          acc[im][t] = __builtin_amdgcn_mfma_f32_16x16x32_bf16(
              af[im][t][s], bfrag[s], acc[im][t], 0, 0, 0);

#pragma unroll
    for (int im = 0; im < 2; ++im) {
      const int ol = im ? ol1 : ol0;
      float m = -3.0e38f;
#pragma unroll
      for (int t = 0; t < MT; ++t)
#pragma unroll
        for (int r = 0; r < 4; ++r) {
          int o = t * 16 + quad * 4 + r;
          if (o < ol) m = fmaxf(m, acc[im][t][r]);
        }
      m = fmaxf(m, __shfl_xor(m, 16));
      m = fmaxf(m, __shfl_xor(m, 32));
      if (quad == 0) wmax[im * (16 * W) + nt * 16 + n16] = m;
    }
  }
  __syncthreads();

  if (tid < 32) {
    const int im = tid >> 4, c = tid & 15;
    const float* wp = wmax + im * (16 * W) + c * W;
    float ssum = 0.f;
    for (int w = 0; w < W; ++w) ssum += wp[w];
    const int cc = cg0 + c;
    pooled[((i0 + im) << 7) + cc] = ssum / (float)cap_l[cc];
  }
}

// ---------------------------------------------------------------------------
// FUSED cooperative kernel: convert -> grid.sync -> t2i(part1+part2) ->
// grid.sync -> loss (block 0). 512 blocks x 256 threads, co-resident at
// 2 blocks/CU (68 KB LDS, <=256 VGPR via launch_bounds).
//
// Loss simplification: max_j relu(M + sc[i][j] - diag[i]) over the
// diag-zeroed matrix == relu(M + offdiag_max_j(sc[i][j]) - diag[i]).
// So we only need off-diagonal row/col maxima of S = p1 + p2.
// ---------------------------------------------------------------------------
__global__ __launch_bounds__(256, 2) void fused_all(
    const float* __restrict__ im, const float* __restrict__ s,
    const float* __restrict__ pred, const float* __restrict__ crp,
    const int* __restrict__ im_l, const int* __restrict__ s_l,
    const int* __restrict__ pred_l, const int* __restrict__ crl,
    unsigned short* __restrict__ imb, unsigned short* __restrict__ sb,
    unsigned short* __restrict__ pb,  unsigned short* __restrict__ cb,
    float* __restrict__ p1, float* __restrict__ p2, float* __restrict__ out)
{
  __shared__ union {
    float wmax[2 * 16 * 50];                       // phase 1 scratch (6.4 KB)
    struct {                                       // phase 2 scratch (~66.6 KB)
      float S[128][129];
      float rmax[128][2];
      float cmax[2][128];
      float wsum[4];
    } L;
  } sh;

  cg::grid_group grid = cg::this_grid();
  const int tid = threadIdx.x;

  // ---- Phase 0: fp32 -> bf16 conversion, 1280 units/block, exact cover ----
  {
    const int base = (int)blockIdx.x * 1280 + tid;
#pragma unroll
    for (int k = 0; k < 5; ++k) {
      const int u = base + k * 256;                // 0 .. 655359, exact
      if (u < 196608)      conv_unit<36, 48>(im,   imb, u);
      else if (u < 401408) conv_unit<50, 50>(s,    sb,  u - 196608);
      else if (u < 532480) conv_unit<25, 32>(pred, pb,  u - 401408);
      else                 conv_unit<30, 30>(crp,  cb,  u - 532480);
    }
  }
  __threadfence();
  grid.sync();

  // ---- Phase 1: both t2i GEMM-pool stages, same block does part1+part2 ----
  t2i_im2<3, 50>(imb, sb, im_l, s_l, p1, (int)blockIdx.x, sh.wmax);
  __syncthreads();                                 // protect wmax reuse
  t2i_im2<2, 30>(pb, cb, pred_l, crl, p2, (int)blockIdx.x, sh.wmax);
  __threadfence();
  grid.sync();

  // ---- Phase 2: hinge loss on block 0 only ----
  if (blockIdx.x != 0) return;

  const int h = tid >> 7, j = tid & 127;
  for (int rr = 0; rr < 64; ++rr) {
    const int row = h * 64 + rr;
    sh.L.S[row][j] = p1[row * 128 + j] + p2[row * 128 + j];
  }
  __syncthreads();

  {  // row off-diagonal max: 2 threads per row, 64 cols each
    const int row = tid >> 1, half = tid & 1;
    float m = -3.0e38f;
    for (int k = 0; k < 64; ++k) {
      const int c = half * 64 + k;
      const float vv = sh.L.S[row][c];
      m = (c == row) ? m : fmaxf(m, vv);
    }
    sh.L.rmax[row][half] = m;
  }
  {  // col off-diagonal max: thread (h,j) scans its 64-row half of column j
    float m = -3.0e38f;
    for (int rr = 0; rr < 64; ++rr) {
      const int row = h * 64 + rr;
      const float vv = sh.L.S[row][j];
      m = (row == j) ? m : fmaxf(m, vv);
    }
    sh.L.cmax[h][j] = m;
  }
  __syncthreads();

  float v = 0.f;
  if (tid < 128) {
    const float d  = sh.L.S[tid][tid];
    const float rm = fmaxf(sh.L.rmax[tid][0], sh.L.rmax[tid][1]);
    const float cm = fmaxf(sh.L.cmax[0][tid], sh.L.cmax[1][tid]);
    v = fmaxf(0.2f + rm - d, 0.f) + fmaxf(0.2f + cm - d, 0.f);
  }
#pragma unroll
  for (int o = 32; o; o >>= 1) v += __shfl_xor(v, o);
  if ((tid & 63) == 0) sh.L.wsum[tid >> 6] = v;
  __syncthreads();
  if (tid == 0)
    out[0] = sh.L.wsum[0] + sh.L.wsum[1] + sh.L.wsum[2] + sh.L.wsum[3];
}

// ===========================================================================
// Fallback path (3 separate kernels) — used only if the cooperative launch
// is rejected (e.g. capture-unsupported). Identical to the verified R-series.
// ===========================================================================
__global__ __launch_bounds__(256) void convert_all(
    const float* __restrict__ im, const float* __restrict__ s,
    const float* __restrict__ pred, const float* __restrict__ crp,
    unsigned short* __restrict__ imb, unsigned short* __restrict__ sb,
    unsigned short* __restrict__ pb, unsigned short* __restrict__ cb)
{
  int b = blockIdx.x;
  const float* src; unsigned short* dst; int O, OP, base;
  if (b < 768)       { src = im;   dst = imb; O = 36; OP = 48; base = 0; }
  else if (b < 1568) { src = s;    dst = sb;  O = 50; OP = 50; base = 768; }
  else if (b < 2080) { src = pred; dst = pb;  O = 25; OP = 32; base = 1568; }
  else               { src = crp;  dst = cb;  O = 30; OP = 30; base = 2080; }
  int tid = (b - base) * 256 + (int)threadIdx.x;
  int total = 128 * OP * 32;
  if (tid >= total) return;
  int d4 = tid & 31;
  int o  = (tid >> 5) % OP;
  int bb = tid / (OP * 32);
  unsigned short r0 = 0, r1 = 0, r2 = 0, r3 = 0;
  if (o < O) {
    const float4 v = *(const float4*)(src + ((bb * O + o) << 7) + (d4 << 2));
    r0 = f2bf(v.x); r1 = f2bf(v.y); r2 = f2bf(v.z); r3 = f2bf(v.w);
  }
  ushort4 outv; outv.x = r0; outv.y = r1; outv.z = r2; outv.w = r3;
  *(ushort4*)(dst + (size_t)tid * 4) = outv;
}

__global__ __launch_bounds__(256) void t2i_both(
    const unsigned short* __restrict__ imb, const unsigned short* __restrict__ sb,
    const unsigned short* __restrict__ pb,  const unsigned short* __restrict__ cb,
    const int* __restrict__ im_l, const int* __restrict__ s_l,
    const int* __restrict__ pred_l, const int* __restrict__ crl,
    float* __restrict__ p1, float* __restrict__ p2)
{
  __shared__ float wmax[2 * 16 * 50];
  if (blockIdx.x < 512) t2i_im2<3, 50>(imb, sb, im_l, s_l, p1, blockIdx.x, wmax);
  else                  t2i_im2<2, 30>(pb, cb, pred_l, crl, p2, blockIdx.x - 512, wmax);
}

__global__ __launch_bounds__(1024) void loss_kernel(
    const float* __restrict__ p1, const float* __restrict__ p2,
    float* __restrict__ out)
{
  __shared__ float diag[128];
  __shared__ int   rowmaxi[128];
  __shared__ float colmax[8][128];
  __shared__ float wred[16];
  const int tid = threadIdx.x;
  const int sub = tid >> 7, j = tid & 127;
  if (sub == 0) {
    diag[j] = p1[j * 129] + p2[j * 129];
    rowmaxi[j] = 0;
  }
  __syncthreads();

  float colp = 0.f;
#pragma unroll
  for (int rr = 0; rr < 16; ++rr) {
    const int row = sub * 16 + rr;
    const float sc = p1[row * 128 + j] + p2[row * 128 + j];
    const float dr = diag[row];
    float rh = (j == row) ? 0.f : fmaxf(0.2f + sc - dr, 0.f);
    const float ch = (j == row) ? 0.f : fmaxf(0.2f + sc - diag[j], 0.f);
    colp = fmaxf(colp, ch);
#pragma unroll
    for (int o = 32; o; o >>= 1) rh = fmaxf(rh, __shfl_xor(rh, o));
    if ((tid & 63) == 0) atomicMax(&rowmaxi[row], __float_as_int(rh));
  }
  colmax[sub][j] = colp;
  __syncthreads();
  if (sub < 4) colmax[sub][j] = fmaxf(colmax[sub][j], colmax[sub + 4][j]);
  __syncthreads();
  if (sub < 2) colmax[sub][j] = fmaxf(colmax[sub][j], colmax[sub + 2][j]);
  __syncthreads();
  if (sub < 1) colmax[0][j] = fmaxf(colmax[0][j], colmax[1][j]);
  __syncthreads();

  float v = 0.f;
  if (tid < 128)      v = __int_as_float(rowmaxi[tid]);
  else if (tid < 256) v = colmax[0][tid - 128];
#pragma unroll
  for (int o = 32; o; o >>= 1) v += __shfl_xor(v, o);
  if ((tid & 63) == 0) wred[tid >> 6] = v;
  __syncthreads();
  if (tid == 0) {
    float sfin = 0.f;
    for (int k = 0; k < 16; ++k) sfin += wred[k];
    out[0] = sfin;
  }
}

// ---------------------------------------------------------------------------
extern "C" void kernel_launch(void* const* d_in, const int* in_sizes, int n_in,
                              void* d_out, int out_size, void* d_ws, size_t ws_size,
                              hipStream_t stream)
{
  const float* im     = (const float*)d_in[0];
  const int*   im_l   = (const int*)  d_in[1];
  const float* s      = (const float*)d_in[2];
  const int*   s_l    = (const int*)  d_in[3];
  const float* pred   = (const float*)d_in[4];
  const int*   pred_l = (const int*)  d_in[5];
  // d_in[6], d_in[7] unused by the reference.
  const float* crp    = (const float*)d_in[8];
  const int*   crl    = (const int*)  d_in[9];

  char* ws = (char*)d_ws;
  const size_t off_imb = 0;
  const size_t off_sb  = off_imb + (size_t)128 * 48 * 128 * 2;
  const size_t off_pb  = off_sb  + (size_t)128 * 50 * 128 * 2;
  const size_t off_cb  = off_pb  + (size_t)128 * 32 * 128 * 2;
  const size_t off_p1  = off_cb  + (size_t)128 * 30 * 128 * 2;
  const size_t off_p2  = off_p1  + (size_t)128 * 128 * 4;

  unsigned short* imb = (unsigned short*)(ws + off_imb);
  unsigned short* sb  = (unsigned short*)(ws + off_sb);
  unsigned short* pb  = (unsigned short*)(ws + off_pb);
  unsigned short* cb  = (unsigned short*)(ws + off_cb);
  float* p1 = (float*)(ws + off_p1);
  float* p2 = (float*)(ws + off_p2);
  float* outp = (float*)d_out;

  void* args[] = {
    (void*)&im, (void*)&s, (void*)&pred, (void*)&crp,
    (void*)&im_l, (void*)&s_l, (void*)&pred_l, (void*)&crl,
    (void*)&imb, (void*)&sb, (void*)&pb, (void*)&cb,
    (void*)&p1, (void*)&p2, (void*)&outp
  };
  hipError_t e = hipLaunchCooperativeKernel((const void*)fused_all,
                                            dim3(512), dim3(256),
                                            args, 0, stream);
  if (e != hipSuccess) {
    (void)hipGetLastError();   // clear sticky error, fall back to 3 launches
    hipLaunchKernelGGL(convert_all, dim3(2560), dim3(256), 0, stream,
                       im, s, pred, crp, imb, sb, pb, cb);
    hipLaunchKernelGGL(t2i_both, dim3(1024), dim3(256), 0, stream,
                       imb, sb, pb, cb, im_l, s_l, pred_l, crl, p1, p2);
    hipLaunchKernelGGL(loss_kernel, dim3(1), dim3(1024), 0, stream,
                       p1, p2, (float*)d_out);
  }
}

// Round 2
// 155.331 us; speedup vs baseline: 2.2270x; 2.2270x over previous
//
#include <hip/hip_runtime.h>

typedef __bf16 bf16x8 __attribute__((ext_vector_type(8)));
typedef float f32x4 __attribute__((ext_vector_type(4)));
typedef unsigned int u32x4 __attribute__((ext_vector_type(4)));

__device__ __forceinline__ unsigned short f2bf(float f) {
  unsigned int u = __float_as_uint(f);
  u += 0x7FFFu + ((u >> 16) & 1u);   // round-to-nearest-even
  return (unsigned short)(u >> 16);
}

__device__ __forceinline__ bf16x8 load_frag(const unsigned short* p) {
  u32x4 v = *(const u32x4*)p;
  return __builtin_bit_cast(bf16x8, v);
}

// ---------------------------------------------------------------------------
// fp32 -> bf16 conversion of all four tensors (object dim zero-padded to a
// multiple of 16 for MFMA M-tiling). Verified R0/R1. Block 0 additionally
// zeroes the completion ticket (workspace is re-poisoned every iteration,
// so init must be in-band, before the t2i dispatch).
// ---------------------------------------------------------------------------
__global__ __launch_bounds__(256) void convert_all(
    const float* __restrict__ im, const float* __restrict__ s,
    const float* __restrict__ pred, const float* __restrict__ crp,
    unsigned short* __restrict__ imb, unsigned short* __restrict__ sb,
    unsigned short* __restrict__ pb, unsigned short* __restrict__ cb,
    unsigned int* __restrict__ ticket)
{
  int b = blockIdx.x;
  if (b == 0 && threadIdx.x == 0) *ticket = 0u;   // kernel-boundary ordering
  const float* src; unsigned short* dst; int O, OP, base;
  if (b < 768)       { src = im;   dst = imb; O = 36; OP = 48; base = 0; }
  else if (b < 1568) { src = s;    dst = sb;  O = 50; OP = 50; base = 768; }
  else if (b < 2080) { src = pred; dst = pb;  O = 25; OP = 32; base = 1568; }
  else               { src = crp;  dst = cb;  O = 30; OP = 30; base = 2080; }
  int tid = (b - base) * 256 + (int)threadIdx.x;          // one thread = 4 floats
  int total = 128 * OP * 32;
  if (tid >= total) return;
  int d4 = tid & 31;
  int o  = (tid >> 5) % OP;
  int bb = tid / (OP * 32);
  unsigned short r0 = 0, r1 = 0, r2 = 0, r3 = 0;
  if (o < O) {
    const float4 v = *(const float4*)(src + ((bb * O + o) << 7) + (d4 << 2));
    r0 = f2bf(v.x); r1 = f2bf(v.y); r2 = f2bf(v.z); r3 = f2bf(v.w);
  }
  ushort4 outv; outv.x = r0; outv.y = r1; outv.z = r2; outv.w = r3;
  *(ushort4*)(dst + (size_t)tid * 4) = outv;
}

// ---------------------------------------------------------------------------
// t2i pooled score, TWO images per block vs one 16-caption group. Verified
// D mapping: col=lane&15 (B-row), row=(lane>>4)*4+reg (object). Unchanged
// from the verified R-series kernel.
// ---------------------------------------------------------------------------
template<int MT, int W>
__device__ __forceinline__ void t2i_im2(
    const unsigned short* __restrict__ A,    // [128, MT*16, 128] bf16
    const unsigned short* __restrict__ Bw,   // [128, W, 128] bf16
    const int* __restrict__ obj_l, const int* __restrict__ cap_l,
    float* __restrict__ pooled,              // [128,128] fp32
    int vb, float* wmax)                     // wmax LDS >= 2*16*W
{
  const int ig  = vb >> 3;             // 0..63 -> images 2*ig, 2*ig+1
  const int i0  = ig * 2;
  const int cg0 = (vb & 7) * 16;
  const int tid = threadIdx.x;
  const int wv = tid >> 6, lane = tid & 63;
  const int quad = lane >> 4, n16 = lane & 15;
  const int ol0 = obj_l[i0], ol1 = obj_l[i0 + 1];

  bf16x8 af[2][MT][4];
#pragma unroll
  for (int im = 0; im < 2; ++im) {
    const unsigned short* Ab =
        A + (((size_t)(i0 + im) * (MT * 16) + n16) << 7) + quad * 8;
#pragma unroll
    for (int t = 0; t < MT; ++t)
#pragma unroll
      for (int s = 0; s < 4; ++s)
        af[im][t][s] = load_frag(Ab + ((t * 16) << 7) + s * 32);
  }

  const unsigned short* Bbase = Bw + (((size_t)cg0 * W + n16) << 7) + quad * 8;

  for (int nt = wv; nt < W; nt += 4) {     // NT = 16*W/16 = W tiles, exact
    const unsigned short* bp = Bbase + ((nt * 16) << 7);
    bf16x8 bfrag[4];
#pragma unroll
    for (int s = 0; s < 4; ++s) bfrag[s] = load_frag(bp + s * 32);

    f32x4 acc[2][MT];
#pragma unroll
    for (int im = 0; im < 2; ++im)
#pragma unroll
      for (int t = 0; t < MT; ++t) { f32x4 z = {0.f,0.f,0.f,0.f}; acc[im][t] = z; }
#pragma unroll
    for (int s = 0; s < 4; ++s)
#pragma unroll
      for (int im = 0; im < 2; ++im)
#pragma unroll
        for (int t = 0; t < MT; ++t)
          acc[im][t] = __builtin_amdgcn_mfma_f32_16x16x32_bf16(
              af[im][t][s], bfrag[s], acc[im][t], 0, 0, 0);

#pragma unroll
    for (int im = 0; im < 2; ++im) {
      const int ol = im ? ol1 : ol0;
      float m = -3.0e38f;
#pragma unroll
      for (int t = 0; t < MT; ++t)
#pragma unroll
        for (int r = 0; r < 4; ++r) {
          int o = t * 16 + quad * 4 + r;
          if (o < ol) m = fmaxf(m, acc[im][t][r]);
        }
      m = fmaxf(m, __shfl_xor(m, 16));
      m = fmaxf(m, __shfl_xor(m, 32));
      if (quad == 0) wmax[im * (16 * W) + nt * 16 + n16] = m;
    }
  }
  __syncthreads();

  if (tid < 32) {
    const int im = tid >> 4, c = tid & 15;
    const float* wp = wmax + im * (16 * W) + c * W;
    float ssum = 0.f;
    for (int w = 0; w < W; ++w) ssum += wp[w];
    const int cc = cg0 + c;
    pooled[((i0 + im) << 7) + cc] = ssum / (float)cap_l[cc];
  }
}

// ---------------------------------------------------------------------------
// t2i (both parts, 1024 blocks as in R0) + hinge loss fused via last-block
// ticket (decoupled-lookback pattern: agent-scope ACQ_REL atomics).
//
// Loss simplification (validated R1): the diag-zeroed hinge row/col max
// equals relu(M + offdiag_max - diag), so only off-diagonal row/col maxima
// of S = p1 + p2 are needed. Winner block (256 thr) reads p1/p2 from L2
// directly; LDS union keeps the block footprint at 6.4 KB so t2i occupancy
// is unchanged vs R0.
// ---------------------------------------------------------------------------
__global__ __launch_bounds__(256) void t2i_both_loss(
    const unsigned short* __restrict__ imb, const unsigned short* __restrict__ sb,
    const unsigned short* __restrict__ pb,  const unsigned short* __restrict__ cb,
    const int* __restrict__ im_l, const int* __restrict__ s_l,
    const int* __restrict__ pred_l, const int* __restrict__ crl,
    float* __restrict__ p1, float* __restrict__ p2,
    unsigned int* __restrict__ ticket, float* __restrict__ out)
{
  __shared__ union {
    float wmax[2 * 16 * 50];                 // t2i scratch (6.4 KB)
    struct {                                 // loss scratch (1.5 KB)
      float cmax[2][128];
      float rmax[2][128];
      float wsum[2];
    } L;
  } sh;
  __shared__ unsigned int winflag;

  const int tid = threadIdx.x;

  if (blockIdx.x < 512) t2i_im2<3, 50>(imb, sb, im_l, s_l, p1, blockIdx.x, sh.wmax);
  else                  t2i_im2<2, 30>(pb, cb, pred_l, crl, p2, blockIdx.x - 512, sh.wmax);

  // ---- last-block-done ticket ----
  __syncthreads();                           // pooled stores + wmax done
  if (tid == 0) {
    unsigned int old = __hip_atomic_fetch_add(ticket, 1u, __ATOMIC_ACQ_REL,
                                              __HIP_MEMORY_SCOPE_AGENT);
    winflag = (old == 1023u) ? 1u : 0u;
  }
  __syncthreads();
  if (winflag == 0u) return;
  __threadfence();                           // belt & suspenders acquire

  // ---- hinge loss on the winner block (256 threads) ----
  const int h = tid >> 7, j = tid & 127;

  // column off-diagonal max (coalesced: lanes sweep j for fixed row)
  {
    float cm = -3.0e38f;
    for (int rr = 0; rr < 64; ++rr) {
      const int row = h * 64 + rr;
      const float v = p1[row * 128 + j] + p2[row * 128 + j];
      cm = (row == j) ? cm : fmaxf(cm, v);
    }
    sh.L.cmax[h][j] = cm;
  }
  // row off-diagonal max (thread (h, i=j) scans its 64-col half of row i)
  {
    float rm = -3.0e38f;
    for (int k = 0; k < 64; ++k) {
      const int c = h * 64 + k;
      const float v = p1[j * 128 + c] + p2[j * 128 + c];
      rm = (c == j) ? rm : fmaxf(rm, v);
    }
    sh.L.rmax[h][j] = rm;
  }
  __syncthreads();

  float v = 0.f;
  if (tid < 128) {
    const float d  = p1[tid * 129] + p2[tid * 129];
    const float rm = fmaxf(sh.L.rmax[0][tid], sh.L.rmax[1][tid]);
    const float cm = fmaxf(sh.L.cmax[0][tid], sh.L.cmax[1][tid]);
    v = fmaxf(0.2f + rm - d, 0.f) + fmaxf(0.2f + cm - d, 0.f);
  }
#pragma unroll
  for (int o = 32; o; o >>= 1) v += __shfl_xor(v, o);
  if (tid == 0)  sh.L.wsum[0] = v;
  if (tid == 64) sh.L.wsum[1] = v;
  __syncthreads();
  if (tid == 0) out[0] = sh.L.wsum[0] + sh.L.wsum[1];
}

// ---------------------------------------------------------------------------
extern "C" void kernel_launch(void* const* d_in, const int* in_sizes, int n_in,
                              void* d_out, int out_size, void* d_ws, size_t ws_size,
                              hipStream_t stream)
{
  const float* im     = (const float*)d_in[0];
  const int*   im_l   = (const int*)  d_in[1];
  const float* s      = (const float*)d_in[2];
  const int*   s_l    = (const int*)  d_in[3];
  const float* pred   = (const float*)d_in[4];
  const int*   pred_l = (const int*)  d_in[5];
  // d_in[6], d_in[7] unused by the reference.
  const float* crp    = (const float*)d_in[8];
  const int*   crl    = (const int*)  d_in[9];

  char* ws = (char*)d_ws;
  const size_t off_imb = 0;
  const size_t off_sb  = off_imb + (size_t)128 * 48 * 128 * 2;
  const size_t off_pb  = off_sb  + (size_t)128 * 50 * 128 * 2;
  const size_t off_cb  = off_pb  + (size_t)128 * 32 * 128 * 2;
  const size_t off_p1  = off_cb  + (size_t)128 * 30 * 128 * 2;
  const size_t off_p2  = off_p1  + (size_t)128 * 128 * 4;
  const size_t off_tk  = off_p2  + (size_t)128 * 128 * 4;

  unsigned short* imb = (unsigned short*)(ws + off_imb);
  unsigned short* sb  = (unsigned short*)(ws + off_sb);
  unsigned short* pb  = (unsigned short*)(ws + off_pb);
  unsigned short* cb  = (unsigned short*)(ws + off_cb);
  float* p1 = (float*)(ws + off_p1);
  float* p2 = (float*)(ws + off_p2);
  unsigned int* ticket = (unsigned int*)(ws + off_tk);

  hipLaunchKernelGGL(convert_all, dim3(2560), dim3(256), 0, stream,
                     im, s, pred, crp, imb, sb, pb, cb, ticket);
  hipLaunchKernelGGL(t2i_both_loss, dim3(1024), dim3(256), 0, stream,
                     imb, sb, pb, cb, im_l, s_l, pred_l, crl,
                     p1, p2, ticket, (float*)d_out);
}

// Round 3
// 139.574 us; speedup vs baseline: 2.4784x; 1.1129x over previous
//
#include <hip/hip_runtime.h>

typedef __bf16 bf16x8 __attribute__((ext_vector_type(8)));
typedef float f32x4 __attribute__((ext_vector_type(4)));
typedef unsigned int u32x4 __attribute__((ext_vector_type(4)));

__device__ __forceinline__ unsigned short f2bf(float f) {
  unsigned int u = __float_as_uint(f);
  u += 0x7FFFu + ((u >> 16) & 1u);   // round-to-nearest-even
  return (unsigned short)(u >> 16);
}

__device__ __forceinline__ bf16x8 load_frag(const unsigned short* p) {
  u32x4 v = *(const u32x4*)p;
  return __builtin_bit_cast(bf16x8, v);
}

// Pin a fragment into VGPRs at this program point: defeats the compiler's
// load-sink/remat (R2 evidence: VGPR_Count=76 < the 96 VGPRs of A-fragment
// state -> 24 global reloads per nt-iteration, L2-BW-bound).
__device__ __forceinline__ void keep(bf16x8& x) {
  asm volatile("" : "+v"(x));
}

// ---------------------------------------------------------------------------
// fp32 -> bf16 conversion of all four tensors (object dim zero-padded to a
// multiple of 16 for MFMA M-tiling). Verified R0/R1/R2.
// ---------------------------------------------------------------------------
__global__ __launch_bounds__(256) void convert_all(
    const float* __restrict__ im, const float* __restrict__ s,
    const float* __restrict__ pred, const float* __restrict__ crp,
    unsigned short* __restrict__ imb, unsigned short* __restrict__ sb,
    unsigned short* __restrict__ pb, unsigned short* __restrict__ cb)
{
  int b = blockIdx.x;
  const float* src; unsigned short* dst; int O, OP, base;
  if (b < 768)       { src = im;   dst = imb; O = 36; OP = 48; base = 0; }
  else if (b < 1568) { src = s;    dst = sb;  O = 50; OP = 50; base = 768; }
  else if (b < 2080) { src = pred; dst = pb;  O = 25; OP = 32; base = 1568; }
  else               { src = crp;  dst = cb;  O = 30; OP = 30; base = 2080; }
  int tid = (b - base) * 256 + (int)threadIdx.x;          // one thread = 4 floats
  int total = 128 * OP * 32;
  if (tid >= total) return;
  int d4 = tid & 31;
  int o  = (tid >> 5) % OP;
  int bb = tid / (OP * 32);
  unsigned short r0 = 0, r1 = 0, r2 = 0, r3 = 0;
  if (o < O) {
    const float4 v = *(const float4*)(src + ((bb * O + o) << 7) + (d4 << 2));
    r0 = f2bf(v.x); r1 = f2bf(v.y); r2 = f2bf(v.z); r3 = f2bf(v.w);
  }
  ushort4 outv; outv.x = r0; outv.y = r1; outv.z = r2; outv.w = r3;
  *(ushort4*)(dst + (size_t)tid * 4) = outv;
}

// ---------------------------------------------------------------------------
// t2i pooled score, TWO images per block vs one 16-caption group.
// R3 changes vs R2:
//  * A fragments pinned in registers (keep()) -> loaded ONCE per block,
//    not re-fetched every nt iteration.
//  * B fragments double-buffered across nt iterations (hide L2 latency
//    under the 24-MFMA chain).
// Verified D mapping: col=lane&15 (B-row), row=(lane>>4)*4+reg (object).
// ---------------------------------------------------------------------------
template<int MT, int W>
__device__ __forceinline__ void t2i_im2(
    const unsigned short* __restrict__ A,    // [128, MT*16, 128] bf16
    const unsigned short* __restrict__ Bw,   // [128, W, 128] bf16
    const int* __restrict__ obj_l, const int* __restrict__ cap_l,
    float* __restrict__ pooled,              // [128,128] fp32
    int vb, float* wmax)                     // wmax LDS >= 2*16*W
{
  const int ig  = vb >> 3;             // 0..63 -> images 2*ig, 2*ig+1
  const int i0  = ig * 2;
  const int cg0 = (vb & 7) * 16;
  const int tid = threadIdx.x;
  const int wv = tid >> 6, lane = tid & 63;
  const int quad = lane >> 4, n16 = lane & 15;
  const int ol0 = obj_l[i0], ol1 = obj_l[i0 + 1];

  // ---- A fragments: load once, pin resident (96 VGPR for MT=3) ----
  bf16x8 af[2][MT][4];
#pragma unroll
  for (int im = 0; im < 2; ++im) {
    const unsigned short* Ab =
        A + (((size_t)(i0 + im) * (MT * 16) + n16) << 7) + quad * 8;
#pragma unroll
    for (int t = 0; t < MT; ++t)
#pragma unroll
      for (int sf = 0; sf < 4; ++sf)
        af[im][t][sf] = load_frag(Ab + ((t * 16) << 7) + sf * 32);
  }
#pragma unroll
  for (int im = 0; im < 2; ++im)
#pragma unroll
    for (int t = 0; t < MT; ++t)
#pragma unroll
      for (int sf = 0; sf < 4; ++sf)
        keep(af[im][t][sf]);

  const unsigned short* Bbase = Bw + (((size_t)cg0 * W + n16) << 7) + quad * 8;

  // ---- prime B double-buffer ----
  bf16x8 bcur[4];
  {
    const unsigned short* bp = Bbase + ((wv * 16) << 7);
#pragma unroll
    for (int sf = 0; sf < 4; ++sf) bcur[sf] = load_frag(bp + sf * 32);
  }

  for (int nt = wv; nt < W; nt += 4) {     // NT = 16*W/16 = W tiles, exact
    // issue next-tile B loads (independent of this iteration's compute)
    const int ntn = (nt + 4 < W) ? (nt + 4) : wv;   // tail reload: harmless
    const unsigned short* bpn = Bbase + ((ntn * 16) << 7);
    bf16x8 bnext[4];
#pragma unroll
    for (int sf = 0; sf < 4; ++sf) bnext[sf] = load_frag(bpn + sf * 32);

    f32x4 acc[2][MT];
#pragma unroll
    for (int im = 0; im < 2; ++im)
#pragma unroll
      for (int t = 0; t < MT; ++t) { f32x4 z = {0.f,0.f,0.f,0.f}; acc[im][t] = z; }
#pragma unroll
    for (int sf = 0; sf < 4; ++sf)
#pragma unroll
      for (int im = 0; im < 2; ++im)
#pragma unroll
        for (int t = 0; t < MT; ++t)
          acc[im][t] = __builtin_amdgcn_mfma_f32_16x16x32_bf16(
              af[im][t][sf], bcur[sf], acc[im][t], 0, 0, 0);

#pragma unroll
    for (int im = 0; im < 2; ++im) {
      const int ol = im ? ol1 : ol0;
      float m = -3.0e38f;
#pragma unroll
      for (int t = 0; t < MT; ++t)
#pragma unroll
        for (int r = 0; r < 4; ++r) {
          int o = t * 16 + quad * 4 + r;
          if (o < ol) m = fmaxf(m, acc[im][t][r]);
        }
      m = fmaxf(m, __shfl_xor(m, 16));
      m = fmaxf(m, __shfl_xor(m, 32));
      if (quad == 0) wmax[im * (16 * W) + nt * 16 + n16] = m;
    }

#pragma unroll
    for (int sf = 0; sf < 4; ++sf) bcur[sf] = bnext[sf];
  }
  __syncthreads();

  if (tid < 32) {
    const int im = tid >> 4, c = tid & 15;
    const float* wp = wmax + im * (16 * W) + c * W;
    float ssum = 0.f;
    for (int w = 0; w < W; ++w) ssum += wp[w];
    const int cc = cg0 + c;
    pooled[((i0 + im) << 7) + cc] = ssum / (float)cap_l[cc];
  }
}

// 512 blocks; each block does its part1 slice then its part2 slice
// (disjoint register lifetimes; one dispatch's worth of launch cost saved).
__global__ __launch_bounds__(256, 2) void t2i_both(
    const unsigned short* __restrict__ imb, const unsigned short* __restrict__ sb,
    const unsigned short* __restrict__ pb,  const unsigned short* __restrict__ cb,
    const int* __restrict__ im_l, const int* __restrict__ s_l,
    const int* __restrict__ pred_l, const int* __restrict__ crl,
    float* __restrict__ p1, float* __restrict__ p2)
{
  __shared__ float wmax[2 * 16 * 50];
  t2i_im2<3, 50>(imb, sb, im_l, s_l, p1, (int)blockIdx.x, wmax);
  __syncthreads();                       // protect wmax reuse across parts
  t2i_im2<2, 30>(pb, cb, pred_l, crl, p2, (int)blockIdx.x, wmax);
}

// ---------------------------------------------------------------------------
// Hinge loss, simplified form validated in R1/R2:
//   max_j relu(M + S[i][j] - diag[i]) over the diag-zeroed matrix
//     == relu(M + offdiag_max_j(S[i][j]) - diag[i])
// One 256-thread block; kernel boundary provides p1/p2 coherence (no fences).
// ---------------------------------------------------------------------------
__global__ __launch_bounds__(256) void loss_kernel(
    const float* __restrict__ p1, const float* __restrict__ p2,
    float* __restrict__ out)
{
  __shared__ float cmax[2][128];
  __shared__ float rmax[2][128];
  __shared__ float wsum[2];
  const int tid = threadIdx.x;
  const int h = tid >> 7, j = tid & 127;

  // column off-diagonal max (coalesced: lanes sweep j for fixed row)
  {
    float cm = -3.0e38f;
    for (int rr = 0; rr < 64; ++rr) {
      const int row = h * 64 + rr;
      const float v = p1[row * 128 + j] + p2[row * 128 + j];
      cm = (row == j) ? cm : fmaxf(cm, v);
    }
    cmax[h][j] = cm;
  }
  // row off-diagonal max (thread (h, i=j) scans its 64-col half of row i)
  {
    float rm = -3.0e38f;
    for (int k = 0; k < 64; ++k) {
      const int c = h * 64 + k;
      const float v = p1[j * 128 + c] + p2[j * 128 + c];
      rm = (c == j) ? rm : fmaxf(rm, v);
    }
    rmax[h][j] = rm;
  }
  __syncthreads();

  float v = 0.f;
  if (tid < 128) {
    const float d  = p1[tid * 129] + p2[tid * 129];
    const float rm = fmaxf(rmax[0][tid], rmax[1][tid]);
    const float cm = fmaxf(cmax[0][tid], cmax[1][tid]);
    v = fmaxf(0.2f + rm - d, 0.f) + fmaxf(0.2f + cm - d, 0.f);
  }
#pragma unroll
  for (int o = 32; o; o >>= 1) v += __shfl_xor(v, o);
  if (tid == 0)  wsum[0] = v;
  if (tid == 64) wsum[1] = v;
  __syncthreads();
  if (tid == 0) out[0] = wsum[0] + wsum[1];
}

// ---------------------------------------------------------------------------
extern "C" void kernel_launch(void* const* d_in, const int* in_sizes, int n_in,
                              void* d_out, int out_size, void* d_ws, size_t ws_size,
                              hipStream_t stream)
{
  const float* im     = (const float*)d_in[0];
  const int*   im_l   = (const int*)  d_in[1];
  const float* s      = (const float*)d_in[2];
  const int*   s_l    = (const int*)  d_in[3];
  const float* pred   = (const float*)d_in[4];
  const int*   pred_l = (const int*)  d_in[5];
  // d_in[6], d_in[7] unused by the reference.
  const float* crp    = (const float*)d_in[8];
  const int*   crl    = (const int*)  d_in[9];

  char* ws = (char*)d_ws;
  const size_t off_imb = 0;
  const size_t off_sb  = off_imb + (size_t)128 * 48 * 128 * 2;
  const size_t off_pb  = off_sb  + (size_t)128 * 50 * 128 * 2;
  const size_t off_cb  = off_pb  + (size_t)128 * 32 * 128 * 2;
  const size_t off_p1  = off_cb  + (size_t)128 * 30 * 128 * 2;
  const size_t off_p2  = off_p1  + (size_t)128 * 128 * 4;

  unsigned short* imb = (unsigned short*)(ws + off_imb);
  unsigned short* sb  = (unsigned short*)(ws + off_sb);
  unsigned short* pb  = (unsigned short*)(ws + off_pb);
  unsigned short* cb  = (unsigned short*)(ws + off_cb);
  float* p1 = (float*)(ws + off_p1);
  float* p2 = (float*)(ws + off_p2);

  hipLaunchKernelGGL(convert_all, dim3(2560), dim3(256), 0, stream,
                     im, s, pred, crp, imb, sb, pb, cb);
  hipLaunchKernelGGL(t2i_both, dim3(512), dim3(256), 0, stream,
                     imb, sb, pb, cb, im_l, s_l, pred_l, crl, p1, p2);
  hipLaunchKernelGGL(loss_kernel, dim3(1), dim3(256), 0, stream,
                     p1, p2, (float*)d_out);
}